// Round 1
// baseline (124.627 us; speedup 1.0000x reference)
//
#include <hip/hip_runtime.h>
#include <hip/hip_fp16.h>

#define DIM 256
#define NN  384

typedef _Float16 v2h __attribute__((ext_vector_type(2)));

__device__ __forceinline__ float fdot2f(__half2 a, __half2 b, float c) {
    // v_dot2_f32_f16: fp16 pair dot-product, fp32 accumulate
    return __builtin_amdgcn_fdot2(__builtin_bit_cast(v2h, a),
                                  __builtin_bit_cast(v2h, b), c, false);
}

// packed relu: max(a, 0) lane-wise on fp16 pair -> v_pk_max_f16
__device__ __forceinline__ __half2 relu2(__half2 a) {
    v2h av = __builtin_bit_cast(v2h, a);
#if __has_builtin(__builtin_elementwise_max)
    v2h zv = {(_Float16)0.0f, (_Float16)0.0f};
    v2h rv = __builtin_elementwise_max(av, zv);
#else
    v2h rv;
    rv.x = av.x > (_Float16)0.0f ? av.x : (_Float16)0.0f;
    rv.y = av.y > (_Float16)0.0f ? av.y : (_Float16)0.0f;
#endif
    return __builtin_bit_cast(__half2, rv);
}

// ---------------- K1: fused transpose+proj ---------------------------------
// xp = x @ Wx^T + bx, emitted as fp16 (xph) and fp16(xp + bi) (xpbh).
// No separate transpose kernel: Wx is streamed through LDS in 32-column
// chunks, stored row-linear (pad 36 dwords -> conflict-free b128 own-row
// reads), with the NEXT chunk register-double-buffered so the L2 stream
// overlaps the FMAs. x rows are block-uniform -> scalar (s_load) path.
// PRJ=6 rows/block -> 1536/6 = 256 blocks = exactly 1 block/CU.
#define PRJ  6
#define WCH  32   // dd columns per LDS chunk
#define WPAD 36   // floats per LDS row: 32 + 4 pad (start bank = 4*lane)
__global__ __launch_bounds__(256) void k_proj(const float* __restrict__ x,
                                              const float* __restrict__ Wx,
                                              const float* __restrict__ bx,
                                              const float* __restrict__ bi,
                                              const float* __restrict__ Wi,
                                              const float* __restrict__ Ws,
                                              __half* __restrict__ xph,
                                              __half* __restrict__ xpbh,
                                              __half* __restrict__ wih,
                                              __half* __restrict__ wsh) {
    __shared__ float wl[DIM][WPAD];          // 36,864 B
    const int t  = threadIdx.x;
    const int r0 = t >> 3;                   // Wx row 0..31 (+32k)
    const int c4 = t & 7;                    // float4 index inside chunk
    const int row0 = blockIdx.x * PRJ;
    const float* xr = x + (size_t)row0 * DIM;

    if (blockIdx.x == 0) {                   // pack Wi/Ws to fp16 once
        wih[t] = __float2half(Wi[t]);
        wsh[t] = __float2half(Ws[t]);
    }

    // prologue: prefetch chunk 0 into registers (8 x float4 / thread)
    const float* wsrc = Wx + c4 * 4;
    float4 pf[8];
#pragma unroll
    for (int k = 0; k < 8; k++)
        pf[k] = *(const float4*)(wsrc + (size_t)(r0 + 32 * k) * DIM);

    float acc[PRJ];
    const float bxe = bx[t];
#pragma unroll
    for (int r = 0; r < PRJ; r++) acc[r] = bxe;

#pragma unroll 1
    for (int c = 0; c < 8; c++) {
        if (c) __syncthreads();              // prior chunk's reads complete
#pragma unroll
        for (int k = 0; k < 8; k++)          // regs -> LDS (b128, min conflict)
            *(float4*)&wl[r0 + 32 * k][c4 * 4] = pf[k];
        __syncthreads();
        if (c < 7) {                         // issue next chunk's loads now;
            const float* nsrc = wsrc + (c + 1) * WCH;  // they fly under compute
#pragma unroll
            for (int k = 0; k < 8; k++)
                pf[k] = *(const float4*)(nsrc + (size_t)(r0 + 32 * k) * DIM);
        }
        const int d0 = c * WCH;
#pragma unroll
        for (int q = 0; q < 8; q++) {
            const float4 wv = *(const float4*)&wl[t][q * 4]; // own row, b128
#pragma unroll
            for (int r = 0; r < PRJ; r++) {
                // uniform address -> s_load_dwordx4 (scalar pipe, free)
                const float4 xv = *(const float4*)(xr + r * DIM + d0 + q * 4);
                acc[r] = fmaf(wv.x, xv.x, acc[r]);
                acc[r] = fmaf(wv.y, xv.y, acc[r]);
                acc[r] = fmaf(wv.z, xv.z, acc[r]);
                acc[r] = fmaf(wv.w, xv.w, acc[r]);
            }
        }
    }

    const float biv = bi[t];
#pragma unroll
    for (int r = 0; r < PRJ; r++) {
        xph [(size_t)(row0 + r) * DIM + t] = __float2half(acc[r]);
        xpbh[(size_t)(row0 + r) * DIM + t] = __float2half(acc[r] + biv);
    }
}

// ---------------- K2: out[b,i,j] = sigmoid( sum_d relu(...)*Ws + bs ) ------
// 48x48 pair tile/block, 3x3 reg tile/thread (rows il+16a, cols jl+16c).
// Grid = 4*8*8 = 256 blocks = exactly 1 block/CU (4 waves, 1/SIMD): perfect
// load balance, and LDS reads/output drop 1.0 -> 0.67 vs the 32x32/2x2
// version (6 row-reads feed 9 outputs). VALU work/output is already the
// algorithmic floor (hadd2+hfma2+pk_max+dot2 per 2 d's). Next-iter LDS
// prefetch (hi/hj rotation) covers ds_read latency at 1 wave/SIMD.
#define LDW 264  // halfs per LDS row: 256 + 8 pad (528 B = 33*16, 16B-aligned)
__global__ __launch_bounds__(256) void k_main(const __half* __restrict__ xpbh,
                                              const __half* __restrict__ xph,
                                              const float* __restrict__ inc,
                                              const __half* __restrict__ wih,
                                              const __half* __restrict__ wsh,
                                              const float* __restrict__ bs,
                                              float* __restrict__ out) {
    __shared__ __half xi[48][LDW]; // xp[i] + bi
    __shared__ __half xj[48][LDW]; // xp[j]
    const int blk = blockIdx.x;           // 256 = 4 * 8 * 8
    const int jt = blk & 7;
    const int it = (blk >> 3) & 7;
    const int b  = blk >> 6;
    const int i0 = it * 48, j0 = jt * 48;
    const int t  = threadIdx.x;
    const int il = t >> 4, jl = t & 15;   // 16 x 16 threads

    // issue inc loads FIRST: latency hides under LDS staging + barrier
    const float* incp = inc + ((size_t)(b * NN) + i0 + il) * NN + j0 + jl;
    float incv[3][3];
#pragma unroll
    for (int a = 0; a < 3; a++)
#pragma unroll
        for (int c = 0; c < 3; c++)
            incv[a][c] = incp[(size_t)(a * 16) * NN + c * 16];
    const float bsv = bs[0];

    const __half* gi = xpbh + (size_t)(b * NN + i0) * DIM;
    const __half* gj = xph  + (size_t)(b * NN + j0) * DIM;
    for (int idx = t; idx < 48 * 32; idx += 256) { // 48 rows x 32 16B-chunks
        const int r = idx >> 5, c = (idx & 31) * 8;
        *(float4*)(&xi[r][c]) = *(const float4*)(gi + r * DIM + c);
        *(float4*)(&xj[r][c]) = *(const float4*)(gj + r * DIM + c);
    }
    __syncthreads();

    __half2 ip[3][3];
    float acc[3][3];
#pragma unroll
    for (int a = 0; a < 3; a++)
#pragma unroll
        for (int c = 0; c < 3; c++) {
            ip[a][c]  = __float2half2_rn(incv[a][c]);
            acc[a][c] = bsv;            // fold bs into accumulator init
        }

    const __half2* wih2 = (const __half2*)wih;
    const __half2* wsh2 = (const __half2*)wsh;

    union F4H { float4 f; __half2 h[4]; };
    F4H hi[3], hj[3];
#pragma unroll
    for (int a = 0; a < 3; a++) {       // prime the software pipeline
        hi[a].f = *(const float4*)&xi[il + 16 * a][0];
        hj[a].f = *(const float4*)&xj[jl + 16 * a][0];
    }

#pragma unroll 4
    for (int d = 0; d < DIM; d += 8) {
        const int dn = (d + 8) & (DIM - 1); // wraps to 0 on last iter (harmless)
        F4H ni[3], nj[3];
#pragma unroll
        for (int a = 0; a < 3; a++) {       // prefetch next iter's fragments
            ni[a].f = *(const float4*)&xi[il + 16 * a][dn];
            nj[a].f = *(const float4*)&xj[jl + 16 * a][dn];
        }
#pragma unroll
        for (int k2 = 0; k2 < 4; k2++) {
            const __half2 wi2 = wih2[(d >> 1) + k2]; // uniform -> s_load
            const __half2 ws2 = wsh2[(d >> 1) + k2]; // uniform -> s_load
#pragma unroll
            for (int a = 0; a < 3; a++)
#pragma unroll
                for (int c = 0; c < 3; c++) {
                    __half2 s = __hadd2(hi[a].h[k2], hj[c].h[k2]);
                    s = __hfma2(ip[a][c], wi2, s);
                    s = relu2(s);
                    acc[a][c] = fdot2f(s, ws2, acc[a][c]);
                }
        }
#pragma unroll
        for (int a = 0; a < 3; a++) { hi[a] = ni[a]; hj[a] = nj[a]; }
    }

    float* op = out + ((size_t)(b * NN) + i0 + il) * NN + j0 + jl;
#pragma unroll
    for (int a = 0; a < 3; a++)
#pragma unroll
        for (int c = 0; c < 3; c++)
            op[(size_t)(a * 16) * NN + c * 16] = 1.f / (1.f + __expf(-acc[a][c]));
}

extern "C" void kernel_launch(void* const* d_in, const int* in_sizes, int n_in,
                              void* d_out, int out_size, void* d_ws, size_t ws_size,
                              hipStream_t stream) {
    const float* x   = (const float*)d_in[0]; // [B,N,DIM]
    const float* inc = (const float*)d_in[1]; // [B,N,N]
    const float* Wx  = (const float*)d_in[2]; // [DIM,DIM]
    const float* bx  = (const float*)d_in[3]; // [DIM]
    const float* Wi  = (const float*)d_in[4]; // [DIM]
    const float* bi  = (const float*)d_in[5]; // [DIM]
    const float* Ws  = (const float*)d_in[6]; // [DIM]
    const float* bs  = (const float*)d_in[7]; // [1]
    float* out = (float*)d_out;

    char* ws = (char*)d_ws;
    __half* xph  = (__half*)ws;                      // 786,432 B
    __half* xpbh = (__half*)(ws + 786432);           // 786,432 B
    __half* wih  = (__half*)(ws + 2 * 786432);       // 512 B
    __half* wsh  = (__half*)(ws + 2 * 786432 + 512); // 512 B

    k_proj<<<256, 256, 0, stream>>>(x, Wx, bx, bi, Wi, Ws, xph, xpbh, wih, wsh);
    k_main<<<256, 256, 0, stream>>>(xpbh, xph, inc, wih, wsh, bs, out);
}

// Round 3
// 99.070 us; speedup vs baseline: 1.2580x; 1.2580x over previous
//
#include <hip/hip_runtime.h>
#include <hip/hip_fp16.h>

#define DIM 256
#define NN  384

typedef _Float16 v2h __attribute__((ext_vector_type(2)));

__device__ __forceinline__ float fdot2f(__half2 a, __half2 b, float c) {
    // v_dot2_f32_f16: fp16 pair dot-product, fp32 accumulate
    return __builtin_amdgcn_fdot2(__builtin_bit_cast(v2h, a),
                                  __builtin_bit_cast(v2h, b), c, false);
}

// packed relu: max(a, 0) lane-wise on fp16 pair -> v_pk_max_f16
__device__ __forceinline__ __half2 relu2(__half2 a) {
    v2h av = __builtin_bit_cast(v2h, a);
#if __has_builtin(__builtin_elementwise_max)
    v2h zv = {(_Float16)0.0f, (_Float16)0.0f};
    v2h rv = __builtin_elementwise_max(av, zv);
#else
    v2h rv;
    rv.x = av.x > (_Float16)0.0f ? av.x : (_Float16)0.0f;
    rv.y = av.y > (_Float16)0.0f ? av.y : (_Float16)0.0f;
#endif
    return __builtin_bit_cast(__half2, rv);
}

// ---------------- K0: transpose Wx [e][d] -> WxT [d][e]; pack Wi/Ws fp16 ---
__global__ __launch_bounds__(256) void k_transpose(const float* __restrict__ W,
                                                   float* __restrict__ WT,
                                                   const float* __restrict__ Wi,
                                                   const float* __restrict__ Ws,
                                                   __half* __restrict__ wih,
                                                   __half* __restrict__ wsh) {
    __shared__ float t[32][33];
    const int bx = blockIdx.x & 7, by = blockIdx.x >> 3;
    const int tx = threadIdx.x & 31, ty = threadIdx.x >> 5; // ty 0..7
#pragma unroll
    for (int k = 0; k < 4; k++) {
        const int r = ty + k * 8;
        t[r][tx] = W[(by * 32 + r) * DIM + bx * 32 + tx];
    }
    if (blockIdx.x == 0) {
        wih[threadIdx.x] = __float2half(Wi[threadIdx.x]);
        wsh[threadIdx.x] = __float2half(Ws[threadIdx.x]);
    }
    __syncthreads();
#pragma unroll
    for (int k = 0; k < 4; k++) {
        const int r = ty + k * 8;
        WT[(bx * 32 + r) * DIM + by * 32 + tx] = t[tx][r];
    }
}

// ---------------- K1: xp = x @ Wx^T + bx ; emit fp16 xp and xp+bi ----------
// 4 rows/block -> 384 blocks (1.5 blocks/CU, 6 waves/CU). x rows staged in
// LDS (uniform-address broadcast reads, ~free); WxT loads coalesced,
// register-double-buffered so the L2 stream hides under the FMAs.
// (Round-1 lesson: do NOT put x in global inside the loop — at low
// occupancy the uniform loads serialize at full L2 latency -> 42 us.)
#define PR 4
__global__ __launch_bounds__(256) void k_proj(const float* __restrict__ x,
                                              const float* __restrict__ WxT,
                                              const float* __restrict__ bx,
                                              const float* __restrict__ bi,
                                              __half* __restrict__ xph,
                                              __half* __restrict__ xpbh) {
    __shared__ float xs[PR][DIM];
    const int row0 = blockIdx.x * PR;
    const int e = threadIdx.x;
    const float* xr = x + (size_t)row0 * DIM;
#pragma unroll
    for (int k = 0; k < PR; k++) xs[k][e] = xr[k * DIM + e];
    __syncthreads();

    float acc[PR];
    const float b0 = bx[e];
#pragma unroll
    for (int r = 0; r < PR; r++) acc[r] = b0;

    float w0 = WxT[0 * DIM + e];
    float w1 = WxT[1 * DIM + e];
    float w2 = WxT[2 * DIM + e];
    float w3 = WxT[3 * DIM + e];
    for (int d = 0; d < DIM; d += 4) {
        const int dn = (d + 4) & (DIM - 1); // wraps to 0 on last iter (harmless)
        const float n0 = WxT[(dn + 0) * DIM + e];
        const float n1 = WxT[(dn + 1) * DIM + e];
        const float n2 = WxT[(dn + 2) * DIM + e];
        const float n3 = WxT[(dn + 3) * DIM + e];
#pragma unroll
        for (int r = 0; r < PR; r++) {
            const float4 xv = *(const float4*)&xs[r][d]; // uniform -> LDS broadcast
            acc[r] = fmaf(xv.x, w0, acc[r]);
            acc[r] = fmaf(xv.y, w1, acc[r]);
            acc[r] = fmaf(xv.z, w2, acc[r]);
            acc[r] = fmaf(xv.w, w3, acc[r]);
        }
        w0 = n0; w1 = n1; w2 = n2; w3 = n3;
    }
    const float biv = bi[e];
#pragma unroll
    for (int r = 0; r < PR; r++) {
        xph [(size_t)(row0 + r) * DIM + e] = __float2half(acc[r]);
        xpbh[(size_t)(row0 + r) * DIM + e] = __float2half(acc[r] + biv);
    }
}

// ---------------- K2: out[b,i,j] = sigmoid( sum_d relu(...)*Ws + bs ) ------
// 48x48 pair tile/block, 3x3 reg tile/thread (rows il+16a, cols jl+16c).
// Grid = 4*8*8 = 256 blocks = exactly 1 block/CU (4 waves, 1/SIMD): perfect
// load balance, and LDS reads/output drop 1.0 -> 0.67 vs the 32x32/2x2
// version (6 row-reads feed 9 outputs). VALU work/output is already the
// algorithmic floor (hadd2+hfma2+pk_max+dot2 per 2 d's). Next-iter LDS
// prefetch (hi/hj rotation) covers ds_read latency at 1 wave/SIMD.
// NOTE: grid MUST be 256 (round-2 crash: launched at 576 -> b=blk>>6 up to 8
// -> OOB on inc/out).
#define LDW 264  // halfs per LDS row: 256 + 8 pad (528 B = 33*16, 16B-aligned)
__global__ __launch_bounds__(256) void k_main(const __half* __restrict__ xpbh,
                                              const __half* __restrict__ xph,
                                              const float* __restrict__ inc,
                                              const __half* __restrict__ wih,
                                              const __half* __restrict__ wsh,
                                              const float* __restrict__ bs,
                                              float* __restrict__ out) {
    __shared__ __half xi[48][LDW]; // xp[i] + bi
    __shared__ __half xj[48][LDW]; // xp[j]
    const int blk = blockIdx.x;           // 256 = 4 * 8 * 8
    const int jt = blk & 7;
    const int it = (blk >> 3) & 7;
    const int b  = blk >> 6;
    const int i0 = it * 48, j0 = jt * 48;
    const int t  = threadIdx.x;
    const int il = t >> 4, jl = t & 15;   // 16 x 16 threads

    // issue inc loads FIRST: latency hides under LDS staging + barrier
    const float* incp = inc + ((size_t)(b * NN) + i0 + il) * NN + j0 + jl;
    float incv[3][3];
#pragma unroll
    for (int a = 0; a < 3; a++)
#pragma unroll
        for (int c = 0; c < 3; c++)
            incv[a][c] = incp[(size_t)(a * 16) * NN + c * 16];
    const float bsv = bs[0];

    const __half* gi = xpbh + (size_t)(b * NN + i0) * DIM;
    const __half* gj = xph  + (size_t)(b * NN + j0) * DIM;
    for (int idx = t; idx < 48 * 32; idx += 256) { // 48 rows x 32 16B-chunks
        const int r = idx >> 5, c = (idx & 31) * 8;
        *(float4*)(&xi[r][c]) = *(const float4*)(gi + r * DIM + c);
        *(float4*)(&xj[r][c]) = *(const float4*)(gj + r * DIM + c);
    }
    __syncthreads();

    __half2 ip[3][3];
    float acc[3][3];
#pragma unroll
    for (int a = 0; a < 3; a++)
#pragma unroll
        for (int c = 0; c < 3; c++) {
            ip[a][c]  = __float2half2_rn(incv[a][c]);
            acc[a][c] = bsv;            // fold bs into accumulator init
        }

    const __half2* wih2 = (const __half2*)wih;
    const __half2* wsh2 = (const __half2*)wsh;

    union F4H { float4 f; __half2 h[4]; };
    F4H hi[3], hj[3];
#pragma unroll
    for (int a = 0; a < 3; a++) {       // prime the software pipeline
        hi[a].f = *(const float4*)&xi[il + 16 * a][0];
        hj[a].f = *(const float4*)&xj[jl + 16 * a][0];
    }

#pragma unroll 4
    for (int d = 0; d < DIM; d += 8) {
        const int dn = (d + 8) & (DIM - 1); // wraps to 0 on last iter (harmless)
        F4H ni[3], nj[3];
#pragma unroll
        for (int a = 0; a < 3; a++) {       // prefetch next iter's fragments
            ni[a].f = *(const float4*)&xi[il + 16 * a][dn];
            nj[a].f = *(const float4*)&xj[jl + 16 * a][dn];
        }
#pragma unroll
        for (int k2 = 0; k2 < 4; k2++) {
            const __half2 wi2 = wih2[(d >> 1) + k2]; // uniform -> s_load
            const __half2 ws2 = wsh2[(d >> 1) + k2]; // uniform -> s_load
#pragma unroll
            for (int a = 0; a < 3; a++)
#pragma unroll
                for (int c = 0; c < 3; c++) {
                    __half2 s = __hadd2(hi[a].h[k2], hj[c].h[k2]);
                    s = __hfma2(ip[a][c], wi2, s);
                    s = relu2(s);
                    acc[a][c] = fdot2f(s, ws2, acc[a][c]);
                }
        }
#pragma unroll
        for (int a = 0; a < 3; a++) { hi[a] = ni[a]; hj[a] = nj[a]; }
    }

    float* op = out + ((size_t)(b * NN) + i0 + il) * NN + j0 + jl;
#pragma unroll
    for (int a = 0; a < 3; a++)
#pragma unroll
        for (int c = 0; c < 3; c++)
            op[(size_t)(a * 16) * NN + c * 16] = 1.f / (1.f + __expf(-acc[a][c]));
}

extern "C" void kernel_launch(void* const* d_in, const int* in_sizes, int n_in,
                              void* d_out, int out_size, void* d_ws, size_t ws_size,
                              hipStream_t stream) {
    const float* x   = (const float*)d_in[0]; // [B,N,DIM]
    const float* inc = (const float*)d_in[1]; // [B,N,N]
    const float* Wx  = (const float*)d_in[2]; // [DIM,DIM]
    const float* bx  = (const float*)d_in[3]; // [DIM]
    const float* Wi  = (const float*)d_in[4]; // [DIM]
    const float* bi  = (const float*)d_in[5]; // [DIM]
    const float* Ws  = (const float*)d_in[6]; // [DIM]
    const float* bs  = (const float*)d_in[7]; // [1]
    float* out = (float*)d_out;

    char* ws = (char*)d_ws;
    float*  WxT  = (float*)ws;                          // 262,144 B
    __half* xph  = (__half*)(ws + 262144);              // 786,432 B
    __half* xpbh = (__half*)(ws + 262144 + 786432);     // 786,432 B
    __half* wih  = (__half*)(ws + 262144 + 2 * 786432); // 512 B
    __half* wsh  = (__half*)(ws + 262144 + 2 * 786432 + 512);

    k_transpose<<<64,  256, 0, stream>>>(Wx, WxT, Wi, Ws, wih, wsh);
    k_proj     <<<384, 256, 0, stream>>>(x, WxT, bx, bi, xph, xpbh);
    k_main     <<<256, 256, 0, stream>>>(xpbh, xph, inc, wih, wsh, bs, out);
}